// Round 1
// baseline (10829.304 us; speedup 1.0000x reference)
//
#include <hip/hip_runtime.h>

// ws layout (bytes):
//   [0, 33554432)            M as double, 256 blocks x 16384 (131072 B each).
//                            After k_svd, first 65536 B of each block's slot is
//                            overwritten with T as float (16384 floats).
//   [33554432, 34603008)     GEMM partials: 8 * 256 * 128 floats

#define NSTR 131               // double stride for 128-row columns in LDS
// float-phase offsets (in floats) inside the shared pool
#define U32_OFF 0
#define V32_OFF 8448
#define RA_OFF  16896
#define RB_OFF  25344
#define WF_OFF  33792
#define POOL_BYTES 151552      // 37888 floats; double phase needs 134144 B

// ---------------- Stage 1: features + conv chain -> M (fp64) ----------------
__global__ __launch_bounds__(256) void k_feat(const float* __restrict__ obs,
        const float* __restrict__ c1w, const float* __restrict__ c1b,
        const float* __restrict__ c2w, const float* __restrict__ c2b,
        double* __restrict__ M)
{
    __shared__ __align__(16) float lds[256*29];
    const int t = threadIdx.x;
    const float4* obs4 = (const float4*)obs;
    float4* lds4 = (float4*)lds;
    const size_t base4 = (size_t)blockIdx.x * 1856;
    for (int idx = t; idx < 1856; idx += 256) lds4[idx] = obs4[base4 + idx];
    __syncthreads();
    const float* o = &lds[t*29];
    double f0=0,f1=0,f2=0,f3=0,f4=0,f5=0;
    #pragma unroll
    for (int d=1; d<5; ++d) f0 += (double)o[d]*d;
    #pragma unroll
    for (int d=1; d<5; ++d) f1 += (double)o[5+d]*d;
    f2 = (double)o[11] + 2.0*(double)o[12];
    #pragma unroll
    for (int d=1; d<8; ++d) f3 += (double)o[13+d]*d;
    #pragma unroll
    for (int d=1; d<6; ++d) f4 += (double)o[21+d]*d;
    f5 = (double)o[28];
    const double w0=c1w[0], w1=c1w[1], w2=c1w[2], w3=c1w[3], b1=c1b[0];
    const double cw0=c2w[0], cw1=c2w[1], b2=c2b[0];
    // conv1 stride2 pad2 k4: 6 -> 4 -> 3 -> 2 ; conv2 k2: -> 1
    double y0 = b1 + f0*w2 + f1*w3;
    double y1 = b1 + f0*w0 + f1*w1 + f2*w2 + f3*w3;
    double y2 = b1 + f2*w0 + f3*w1 + f4*w2 + f5*w3;
    double y3 = b1 + f4*w0 + f5*w1;
    double z0 = b1 + y0*w2 + y1*w3;
    double z1 = b1 + y0*w0 + y1*w1 + y2*w2 + y3*w3;
    double z2 = b1 + y2*w0 + y3*w1;
    double u0 = b1 + z0*w2 + z1*w3;
    double u1 = b1 + z0*w0 + z1*w1 + z2*w2;
    double m  = b2 + u0*cw0 + u1*cw1;
    M[(size_t)blockIdx.x*256 + t] = m;
}

// ---------------- Stage 2: per-batch SVD + QR signs + MLP + T ----------------
__global__ __launch_bounds__(512, 2) void k_svd(
        const float* __restrict__ w1g, const float* __restrict__ w2g,
        double* __restrict__ wsM)
{
    __shared__ __align__(16) char smem[POOL_BYTES];
    double* Ad = (double*)smem;
    float*  Af = (float*)smem;
    __shared__ double sig_d[128];
    __shared__ double sigs_d[64];
    __shared__ float  sigf[64];
    __shared__ double tau[64];
    __shared__ double vjs[64];
    __shared__ int    perm[128];
    __shared__ double redbuf[8];
    __shared__ int    convflag;

    const int t = threadIdx.x;
    const int b = blockIdx.x;
    double* Mg = wsM + (size_t)b*16384;

    // load M column-major into LDS (fp64)
    for (int idx = t; idx < 16384; idx += 512) {
        int r = idx >> 7, c = idx & 127;
        Ad[c*NSTR + r] = Mg[idx];
    }
    __syncthreads();

    // ---- one-sided (Hestenes) Jacobi on columns, fp64 ----
    const int pk = t >> 3;      // pair id 0..63
    const int sub = t & 7;      // lane within pair
    for (int sweep = 0; sweep < 18; ++sweep) {
        double mx = 0.0;
        for (int round = 0; round < 127; ++round) {
            int p, q;
            if (pk == 0) { p = 127; q = round % 127; }
            else { p = (round + pk) % 127; q = (round - pk + 127) % 127; }
            double* Ap = &Ad[p*NSTR + sub*16];
            double* Aq = &Ad[q*NSTR + sub*16];
            double xs[16], ys[16];
            double al = 0.0, be = 0.0, ga = 0.0;
            #pragma unroll
            for (int m = 0; m < 16; ++m) {
                double x = Ap[m], y = Aq[m];
                xs[m] = x; ys[m] = y;
                al = fma(x, x, al); be = fma(y, y, be); ga = fma(x, y, ga);
            }
            al += __shfl_xor(al,1); be += __shfl_xor(be,1); ga += __shfl_xor(ga,1);
            al += __shfl_xor(al,2); be += __shfl_xor(be,2); ga += __shfl_xor(ga,2);
            al += __shfl_xor(al,4); be += __shfl_xor(be,4); ga += __shfl_xor(ga,4);
            double ab = al*be, g2 = ga*ga;
            mx = fmax(mx, g2/ab);
            if (g2 > ab*1e-26) {
                double zeta = (be - al) / (2.0*ga);
                double tt = ((zeta >= 0.0) ? 1.0 : -1.0) / (fabs(zeta) + sqrt(fma(zeta,zeta,1.0)));
                double cc = 1.0 / sqrt(fma(tt,tt,1.0));
                double ss = tt*cc;
                #pragma unroll
                for (int m = 0; m < 16; ++m) {
                    Ap[m] = fma(-ss, ys[m], cc*xs[m]);
                    Aq[m] = fma( ss, xs[m], cc*ys[m]);
                }
            }
            __syncthreads();
        }
        #pragma unroll
        for (int off = 1; off < 64; off <<= 1) mx = fmax(mx, __shfl_xor(mx, off));
        if ((t & 63) == 0) redbuf[t >> 6] = mx;
        __syncthreads();
        if (t == 0) {
            double m0 = redbuf[0];
            for (int i = 1; i < 8; ++i) m0 = fmax(m0, redbuf[i]);
            convflag = (m0 < 1e-26) ? 1 : 0;
        }
        __syncthreads();
        if (convflag) break;
    }
    __syncthreads();

    // ---- column norms, sort descending ----
    if (t < 128) {
        double s = 0.0;
        for (int r = 0; r < 128; ++r) { double v = Ad[t*NSTR + r]; s = fma(v, v, s); }
        sig_d[t] = sqrt(s);
    }
    __syncthreads();
    if (t < 128) {
        double my = sig_d[t]; int rk = 0;
        for (int c = 0; c < 128; ++c) {
            double v = sig_d[c];
            rk += (v > my) || (v == my && c < t);
        }
        perm[rk] = t;
    }
    __syncthreads();
    if (t < 64) { sigs_d[t] = sig_d[perm[t]]; sigf[t] = (float)sig_d[perm[t]]; }
    __syncthreads();

    // ---- compact U64 = A[:,perm[k]]/sigma into cols 0..63 (register-staged) ----
    {
        double tmp[16];
        #pragma unroll
        for (int i = 0; i < 16; ++i) {
            int idx = t + i*512; int k = idx >> 7, r = idx & 127;
            tmp[i] = Ad[perm[k]*NSTR + r] / sigs_d[k];
        }
        __syncthreads();
        #pragma unroll
        for (int i = 0; i < 16; ++i) {
            int idx = t + i*512; int k = idx >> 7, r = idx & 127;
            Ad[k*NSTR + r] = tmp[i];
        }
    }
    __syncthreads();

    // ---- V64 = M^T * U64 * Sigma^{-1} into cols 64..127 ----
    {
        const int j = t & 127, kh = (t >> 7)*16;
        double acc[16];
        #pragma unroll
        for (int m = 0; m < 16; ++m) acc[m] = 0.0;
        for (int r = 0; r < 128; ++r) {
            double mv = Mg[r*128 + j];
            #pragma unroll
            for (int m = 0; m < 16; ++m) acc[m] = fma(mv, Ad[(kh+m)*NSTR + r], acc[m]);
        }
        #pragma unroll
        for (int m = 0; m < 16; ++m) Ad[(64+kh+m)*NSTR + j] = acc[m] / sigs_d[kh+m];
    }
    __syncthreads();

    // ---- Householder QR (LAPACK sign convention) + org2r rebuild, in place ----
    // After this, cols 0..63 = U_st (= Q of qr(U64)) and cols 64..127 = Vq.
    for (int which = 0; which < 2; ++which) {
        const int CB = which ? 64 : 0;
        // geqrf
        for (int j = 0; j < 64; ++j) {
            if (t < 64) {
                double ps = 0.0;
                for (int r = j + t; r < 128; r += 64) { double v = Ad[(CB+j)*NSTR + r]; ps = fma(v, v, ps); }
                #pragma unroll
                for (int off = 1; off < 64; off <<= 1) ps += __shfl_xor(ps, off);
                if (t == 0) {
                    double piv = Ad[(CB+j)*NSTR + j];
                    double nx = sqrt(ps);
                    double vj = piv + ((piv >= 0.0) ? nx : -nx);
                    double vn2 = ps - piv*piv + vj*vj;
                    tau[j] = 2.0 / vn2;
                    vjs[j] = vj;
                    Ad[(CB+j)*NSTR + j] = vj;
                }
            }
            __syncthreads();
            {
                int g = t >> 3, c = j + 1 + g;
                if (c < 64) {
                    double w = 0.0;
                    for (int r = j + sub; r < 128; r += 8)
                        w = fma(Ad[(CB+j)*NSTR + r], Ad[(CB+c)*NSTR + r], w);
                    w += __shfl_xor(w,1); w += __shfl_xor(w,2); w += __shfl_xor(w,4);
                    w *= tau[j];
                    for (int r = j + sub; r < 128; r += 8)
                        Ad[(CB+c)*NSTR + r] -= w * Ad[(CB+j)*NSTR + r];
                }
            }
            __syncthreads();
        }
        // org2r (backward accumulation): Q = H_0 ... H_63 * E
        for (int j = 63; j >= 0; --j) {
            {
                int g = t >> 3, c = j + 1 + g;
                if (c < 64) {
                    double w = 0.0;
                    for (int r = j + sub; r < 128; r += 8)
                        w = fma(Ad[(CB+j)*NSTR + r], Ad[(CB+c)*NSTR + r], w);
                    w += __shfl_xor(w,1); w += __shfl_xor(w,2); w += __shfl_xor(w,4);
                    w *= tau[j];
                    for (int r = j + sub; r < 128; r += 8)
                        Ad[(CB+c)*NSTR + r] -= w * Ad[(CB+j)*NSTR + r];
                }
            }
            __syncthreads();
            if (t < 128) {
                double qv;
                if (t < j) qv = 0.0;
                else {
                    double vt = Ad[(CB+j)*NSTR + t];
                    qv = ((t == j) ? 1.0 : 0.0) - tau[j]*vjs[j]*vt;
                }
                Ad[(CB+j)*NSTR + t] = qv;
            }
            __syncthreads();
        }
    }

    // ---- downcast U_st, Vq to fp32 (register-staged, regions overlap) ----
    {
        float tmpf[16];
        #pragma unroll
        for (int i = 0; i < 16; ++i) {
            int idx = t + i*512; int k = idx >> 7, r = idx & 127;
            tmpf[i] = (float)Ad[k*NSTR + r];
        }
        __syncthreads();
        #pragma unroll
        for (int i = 0; i < 16; ++i) {
            int idx = t + i*512; int k = idx >> 7, r = idx & 127;
            Af[U32_OFF + k*132 + r] = tmpf[i];
        }
        __syncthreads();
        #pragma unroll
        for (int i = 0; i < 16; ++i) {
            int idx = t + i*512; int k = idx >> 7, r = idx & 127;
            tmpf[i] = (float)Ad[(64+k)*NSTR + r];
        }
        __syncthreads();
        #pragma unroll
        for (int i = 0; i < 16; ++i) {
            int idx = t + i*512; int k = idx >> 7, r = idx & 127;
            Af[V32_OFF + k*132 + r] = tmpf[i];
        }
    }
    __syncthreads();

    // ---- MLP chain (fp32): relu chains; layer 3 also scales by sigma ----
    int SRCO = U32_OFF, DSTO = RA_OFF;
    const int n = t & 63, ib = (t >> 6)*16;
    for (int layer = 0; layer < 7; ++layer) {
        const float* wptr = (layer < 4) ? (w1g + layer*4096) : (w2g + (layer-3)*4096);
        for (int idx = t; idx < 4096; idx += 512) Af[WF_OFF + idx] = wptr[idx];
        __syncthreads();
        float acc[16];
        #pragma unroll
        for (int m = 0; m < 16; ++m) acc[m] = 0.f;
        for (int kk = 0; kk < 64; ++kk) {
            float wv = Af[WF_OFF + kk*64 + n];
            const float4* s4 = (const float4*)&Af[SRCO + kk*132 + ib];
            #pragma unroll
            for (int q4 = 0; q4 < 4; ++q4) {
                float4 v4 = s4[q4];
                acc[q4*4+0] = fmaf(v4.x, wv, acc[q4*4+0]);
                acc[q4*4+1] = fmaf(v4.y, wv, acc[q4*4+1]);
                acc[q4*4+2] = fmaf(v4.z, wv, acc[q4*4+2]);
                acc[q4*4+3] = fmaf(v4.w, wv, acc[q4*4+3]);
            }
        }
        float sc = (layer == 3) ? sigf[n] : 1.f;
        #pragma unroll
        for (int q4 = 0; q4 < 4; ++q4) {
            float4 o;
            o.x = fmaxf(acc[q4*4+0], 0.f)*sc;
            o.y = fmaxf(acc[q4*4+1], 0.f)*sc;
            o.z = fmaxf(acc[q4*4+2], 0.f)*sc;
            o.w = fmaxf(acc[q4*4+3], 0.f)*sc;
            ((float4*)&Af[DSTO + n*132 + ib])[q4] = o;
        }
        __syncthreads();
        SRCO = DSTO; DSTO = (DSTO == RA_OFF) ? RB_OFF : RA_OFF;
    }

    // ---- T = r @ Vh_st, write fp32 into this block's own M slot ----
    {
        float* Tb = (float*)((char*)wsM + (size_t)b*131072);
        const int j2 = t & 127, ih = (t >> 7)*32;
        float acc2[32];
        #pragma unroll
        for (int m = 0; m < 32; ++m) acc2[m] = 0.f;
        for (int kk = 0; kk < 64; ++kk) {
            float vv = Af[V32_OFF + kk*132 + j2];
            const float4* r4 = (const float4*)&Af[RA_OFF + kk*132 + ih];
            #pragma unroll
            for (int q4 = 0; q4 < 8; ++q4) {
                float4 v4 = r4[q4];
                acc2[q4*4+0] = fmaf(v4.x, vv, acc2[q4*4+0]);
                acc2[q4*4+1] = fmaf(v4.y, vv, acc2[q4*4+1]);
                acc2[q4*4+2] = fmaf(v4.z, vv, acc2[q4*4+2]);
                acc2[q4*4+3] = fmaf(v4.w, vv, acc2[q4*4+3]);
            }
        }
        #pragma unroll
        for (int m = 0; m < 32; ++m) Tb[(size_t)(ih+m)*128 + j2] = acc2[m];
    }
}

// ---------------- Stage 3: out = weightsO @ vec(T) per batch (K-split) ----------------
__global__ __launch_bounds__(256) void k_out(const char* __restrict__ wsbase,
        const float* __restrict__ wO, float* __restrict__ part)
{
    __shared__ float Wt[128*65];
    __shared__ float Tt[8*64];
    const int t = threadIdx.x;
    const int bt = blockIdx.x & 31, ks = blockIdx.x >> 5;
    const int a = t & 127, bh = (t >> 7)*4;
    float acc[4] = {0.f, 0.f, 0.f, 0.f};
    for (int cc = 0; cc < 32; ++cc) {
        const int kbase = ks*2048 + cc*64;
        __syncthreads();
        for (int idx = t; idx < 8192; idx += 256) {
            int aa = idx >> 6, nn = idx & 63;
            Wt[aa*65 + nn] = wO[aa*16384 + kbase + nn];
        }
        for (int idx = t; idx < 512; idx += 256) {
            int bl = idx >> 6, nn = idx & 63;
            const float* Tb = (const float*)(wsbase + (size_t)(bt*8 + bl)*131072);
            Tt[bl*64 + nn] = Tb[kbase + nn];
        }
        __syncthreads();
        for (int nn = 0; nn < 64; ++nn) {
            float wv = Wt[a*65 + nn];
            #pragma unroll
            for (int m = 0; m < 4; ++m) acc[m] = fmaf(Tt[(bh+m)*64 + nn], wv, acc[m]);
        }
    }
    #pragma unroll
    for (int m = 0; m < 4; ++m)
        part[ks*32768 + (bt*8 + bh + m)*128 + a] = acc[m];
}

__global__ __launch_bounds__(256) void k_red(const float* __restrict__ part,
                                             float* __restrict__ out)
{
    int i = blockIdx.x*256 + threadIdx.x;
    float s = 0.f;
    #pragma unroll
    for (int ks = 0; ks < 8; ++ks) s += part[ks*32768 + i];
    out[i] = s;
}

extern "C" void kernel_launch(void* const* d_in, const int* in_sizes, int n_in,
                              void* d_out, int out_size, void* d_ws, size_t ws_size,
                              hipStream_t stream)
{
    (void)in_sizes; (void)n_in; (void)out_size; (void)ws_size;
    const float* obs = (const float*)d_in[0];
    const float* w1  = (const float*)d_in[1];
    const float* w2  = (const float*)d_in[2];
    const float* wO  = (const float*)d_in[3];
    const float* c1w = (const float*)d_in[4];
    const float* c1b = (const float*)d_in[5];
    const float* c2w = (const float*)d_in[6];
    const float* c2b = (const float*)d_in[7];
    double* M = (double*)d_ws;
    float* part = (float*)((char*)d_ws + 33554432);

    k_feat<<<dim3(16384), dim3(256), 0, stream>>>(obs, c1w, c1b, c2w, c2b, M);
    k_svd <<<dim3(256),   dim3(512), 0, stream>>>(w1, w2, M);
    k_out <<<dim3(256),   dim3(256), 0, stream>>>((const char*)d_ws, wO, part);
    k_red <<<dim3(128),   dim3(256), 0, stream>>>(part, (float*)d_out);
}

// Round 2
// 3804.636 us; speedup vs baseline: 2.8463x; 2.8463x over previous
//
#include <hip/hip_runtime.h>

// ws layout (bytes):
//   [0, 33554432)            M as double, 256 blocks x 16384 (131072 B each).
//                            After k_svd, first 65536 B of each block's slot is
//                            overwritten with T as float (16384 floats).
//   [33554432, 34603008)     GEMM partials: 8 * 256 * 128 floats

#define NSTR 132               // double stride for 128-row columns in LDS (EVEN: 16B-aligned double2)
// float-phase offsets (in floats) inside the shared pool
#define U32_OFF 0
#define V32_OFF 8448
#define RA_OFF  16896
#define RB_OFF  25344
#define WF_OFF  33792
#define POOL_BYTES 151552      // 37888 floats; double phase needs 128*132*8 = 135168 B

// ---------------- Stage 1: features + conv chain -> M (fp64) ----------------
__global__ __launch_bounds__(256) void k_feat(const float* __restrict__ obs,
        const float* __restrict__ c1w, const float* __restrict__ c1b,
        const float* __restrict__ c2w, const float* __restrict__ c2b,
        double* __restrict__ M)
{
    __shared__ __align__(16) float lds[256*29];
    const int t = threadIdx.x;
    const float4* obs4 = (const float4*)obs;
    float4* lds4 = (float4*)lds;
    const size_t base4 = (size_t)blockIdx.x * 1856;
    for (int idx = t; idx < 1856; idx += 256) lds4[idx] = obs4[base4 + idx];
    __syncthreads();
    const float* o = &lds[t*29];
    double f0=0,f1=0,f2=0,f3=0,f4=0,f5=0;
    #pragma unroll
    for (int d=1; d<5; ++d) f0 += (double)o[d]*d;
    #pragma unroll
    for (int d=1; d<5; ++d) f1 += (double)o[5+d]*d;
    f2 = (double)o[11] + 2.0*(double)o[12];
    #pragma unroll
    for (int d=1; d<8; ++d) f3 += (double)o[13+d]*d;
    #pragma unroll
    for (int d=1; d<6; ++d) f4 += (double)o[21+d]*d;
    f5 = (double)o[28];
    const double w0=c1w[0], w1=c1w[1], w2=c1w[2], w3=c1w[3], b1=c1b[0];
    const double cw0=c2w[0], cw1=c2w[1], b2=c2b[0];
    // conv1 stride2 pad2 k4: 6 -> 4 -> 3 -> 2 ; conv2 k2: -> 1
    double y0 = b1 + f0*w2 + f1*w3;
    double y1 = b1 + f0*w0 + f1*w1 + f2*w2 + f3*w3;
    double y2 = b1 + f2*w0 + f3*w1 + f4*w2 + f5*w3;
    double y3 = b1 + f4*w0 + f5*w1;
    double z0 = b1 + y0*w2 + y1*w3;
    double z1 = b1 + y0*w0 + y1*w1 + y2*w2 + y3*w3;
    double z2 = b1 + y2*w0 + y3*w1;
    double u0 = b1 + z0*w2 + z1*w3;
    double u1 = b1 + z0*w0 + z1*w1 + z2*w2;
    double m  = b2 + u0*cw0 + u1*cw1;
    M[(size_t)blockIdx.x*256 + t] = m;
}

// ---------------- Stage 2: per-batch SVD + QR signs + MLP + T ----------------
__global__ __launch_bounds__(512, 2) void k_svd(
        const float* __restrict__ w1g, const float* __restrict__ w2g,
        double* __restrict__ wsM)
{
    __shared__ __align__(16) char smem[POOL_BYTES];
    double* Ad = (double*)smem;
    float*  Af = (float*)smem;
    __shared__ double sig_d[128];
    __shared__ double sigs_d[64];
    __shared__ float  sigf[64];
    __shared__ double tau[64];
    __shared__ double vjs[64];
    __shared__ int    perm[128];
    __shared__ double redbuf[8];
    __shared__ int    convflag;

    const int t = threadIdx.x;
    const int b = blockIdx.x;
    double* Mg = wsM + (size_t)b*16384;

    // load M column-major into LDS (fp64)
    for (int idx = t; idx < 16384; idx += 512) {
        int r = idx >> 7, c = idx & 127;
        Ad[c*NSTR + r] = Mg[idx];
    }
    __syncthreads();

    // ---- one-sided (Hestenes) Jacobi on columns, fp64 ----
    // Lane `sub` (0..7) of pair `pk` owns rows {2*sub + 16*m, 2*sub + 16*m + 1},
    // m = 0..7, accessed as double2 (ds_read_b128). With NSTR even, a pair's 8
    // lanes cover exactly 32 consecutive dwords -> all 32 banks once -> the
    // hardware-minimum bank occupancy for a wave64 b128 access (conflict-free).
    const int pk = t >> 3;      // pair id 0..63
    const int sub = t & 7;      // lane within pair
    for (int sweep = 0; sweep < 16; ++sweep) {
        double mx = 0.0;
        for (int round = 0; round < 127; ++round) {
            int p, q;
            if (pk == 0) { p = 127; q = round % 127; }
            else { p = (round + pk) % 127; q = (round - pk + 127) % 127; }
            double2* Ap = (double2*)&Ad[p*NSTR + 2*sub];
            double2* Aq = (double2*)&Ad[q*NSTR + 2*sub];
            double2 xs[8], ys[8];
            double al = 0.0, be = 0.0, ga = 0.0;
            #pragma unroll
            for (int m = 0; m < 8; ++m) {
                double2 x = Ap[m*8], y = Aq[m*8];
                xs[m] = x; ys[m] = y;
                al = fma(x.x, x.x, al); al = fma(x.y, x.y, al);
                be = fma(y.x, y.x, be); be = fma(y.y, y.y, be);
                ga = fma(x.x, y.x, ga); ga = fma(x.y, y.y, ga);
            }
            al += __shfl_xor(al,1); be += __shfl_xor(be,1); ga += __shfl_xor(ga,1);
            al += __shfl_xor(al,2); be += __shfl_xor(be,2); ga += __shfl_xor(ga,2);
            al += __shfl_xor(al,4); be += __shfl_xor(be,4); ga += __shfl_xor(ga,4);
            double ab = al*be, g2 = ga*ga;
            mx = fmax(mx, g2/ab);
            if (g2 > ab*1e-28) {
                double zeta = (be - al) / (2.0*ga);
                double tt = ((zeta >= 0.0) ? 1.0 : -1.0) / (fabs(zeta) + sqrt(fma(zeta,zeta,1.0)));
                double cc = 1.0 / sqrt(fma(tt,tt,1.0));
                double ss = tt*cc;
                #pragma unroll
                for (int m = 0; m < 8; ++m) {
                    double2 np, nq;
                    np.x = fma(-ss, ys[m].x, cc*xs[m].x);
                    np.y = fma(-ss, ys[m].y, cc*xs[m].y);
                    nq.x = fma( ss, xs[m].x, cc*ys[m].x);
                    nq.y = fma( ss, xs[m].y, cc*ys[m].y);
                    Ap[m*8] = np;
                    Aq[m*8] = nq;
                }
            }
            __syncthreads();
        }
        #pragma unroll
        for (int off = 1; off < 64; off <<= 1) mx = fmax(mx, __shfl_xor(mx, off));
        if ((t & 63) == 0) redbuf[t >> 6] = mx;
        __syncthreads();
        if (t == 0) {
            double m0 = redbuf[0];
            for (int i = 1; i < 8; ++i) m0 = fmax(m0, redbuf[i]);
            convflag = (m0 < 1e-20) ? 1 : 0;
        }
        __syncthreads();
        if (convflag) break;
    }
    __syncthreads();

    // ---- column norms, sort descending ----
    if (t < 128) {
        double s = 0.0;
        for (int r = 0; r < 128; ++r) { double v = Ad[t*NSTR + r]; s = fma(v, v, s); }
        sig_d[t] = sqrt(s);
    }
    __syncthreads();
    if (t < 128) {
        double my = sig_d[t]; int rk = 0;
        for (int c = 0; c < 128; ++c) {
            double v = sig_d[c];
            rk += (v > my) || (v == my && c < t);
        }
        perm[rk] = t;
    }
    __syncthreads();
    if (t < 64) { sigs_d[t] = sig_d[perm[t]]; sigf[t] = (float)sig_d[perm[t]]; }
    __syncthreads();

    // ---- compact U64 = A[:,perm[k]]/sigma into cols 0..63 (register-staged) ----
    {
        double tmp[16];
        #pragma unroll
        for (int i = 0; i < 16; ++i) {
            int idx = t + i*512; int k = idx >> 7, r = idx & 127;
            tmp[i] = Ad[perm[k]*NSTR + r] / sigs_d[k];
        }
        __syncthreads();
        #pragma unroll
        for (int i = 0; i < 16; ++i) {
            int idx = t + i*512; int k = idx >> 7, r = idx & 127;
            Ad[k*NSTR + r] = tmp[i];
        }
    }
    __syncthreads();

    // ---- V64 = M^T * U64 * Sigma^{-1} into cols 64..127 ----
    {
        const int j = t & 127, kh = (t >> 7)*16;
        double acc[16];
        #pragma unroll
        for (int m = 0; m < 16; ++m) acc[m] = 0.0;
        for (int r = 0; r < 128; ++r) {
            double mv = Mg[r*128 + j];
            #pragma unroll
            for (int m = 0; m < 16; ++m) acc[m] = fma(mv, Ad[(kh+m)*NSTR + r], acc[m]);
        }
        #pragma unroll
        for (int m = 0; m < 16; ++m) Ad[(64+kh+m)*NSTR + j] = acc[m] / sigs_d[kh+m];
    }
    __syncthreads();

    // ---- Householder QR (LAPACK sign convention) + org2r rebuild, in place ----
    // After this, cols 0..63 = U_st (= Q of qr(U64)) and cols 64..127 = Vq.
    for (int which = 0; which < 2; ++which) {
        const int CB = which ? 64 : 0;
        // geqrf
        for (int j = 0; j < 64; ++j) {
            if (t < 64) {
                double ps = 0.0;
                for (int r = j + t; r < 128; r += 64) { double v = Ad[(CB+j)*NSTR + r]; ps = fma(v, v, ps); }
                #pragma unroll
                for (int off = 1; off < 64; off <<= 1) ps += __shfl_xor(ps, off);
                if (t == 0) {
                    double piv = Ad[(CB+j)*NSTR + j];
                    double nx = sqrt(ps);
                    double vj = piv + ((piv >= 0.0) ? nx : -nx);
                    double vn2 = ps - piv*piv + vj*vj;
                    tau[j] = 2.0 / vn2;
                    vjs[j] = vj;
                    Ad[(CB+j)*NSTR + j] = vj;
                }
            }
            __syncthreads();
            {
                int g = t >> 3, c = j + 1 + g;
                if (c < 64) {
                    double w = 0.0;
                    for (int r = j + sub; r < 128; r += 8)
                        w = fma(Ad[(CB+j)*NSTR + r], Ad[(CB+c)*NSTR + r], w);
                    w += __shfl_xor(w,1); w += __shfl_xor(w,2); w += __shfl_xor(w,4);
                    w *= tau[j];
                    for (int r = j + sub; r < 128; r += 8)
                        Ad[(CB+c)*NSTR + r] -= w * Ad[(CB+j)*NSTR + r];
                }
            }
            __syncthreads();
        }
        // org2r (backward accumulation): Q = H_0 ... H_63 * E
        for (int j = 63; j >= 0; --j) {
            {
                int g = t >> 3, c = j + 1 + g;
                if (c < 64) {
                    double w = 0.0;
                    for (int r = j + sub; r < 128; r += 8)
                        w = fma(Ad[(CB+j)*NSTR + r], Ad[(CB+c)*NSTR + r], w);
                    w += __shfl_xor(w,1); w += __shfl_xor(w,2); w += __shfl_xor(w,4);
                    w *= tau[j];
                    for (int r = j + sub; r < 128; r += 8)
                        Ad[(CB+c)*NSTR + r] -= w * Ad[(CB+j)*NSTR + r];
                }
            }
            __syncthreads();
            if (t < 128) {
                double qv;
                if (t < j) qv = 0.0;
                else {
                    double vt = Ad[(CB+j)*NSTR + t];
                    qv = ((t == j) ? 1.0 : 0.0) - tau[j]*vjs[j]*vt;
                }
                Ad[(CB+j)*NSTR + t] = qv;
            }
            __syncthreads();
        }
    }

    // ---- downcast U_st, Vq to fp32 (register-staged, regions overlap) ----
    {
        float tmpf[16];
        #pragma unroll
        for (int i = 0; i < 16; ++i) {
            int idx = t + i*512; int k = idx >> 7, r = idx & 127;
            tmpf[i] = (float)Ad[k*NSTR + r];
        }
        __syncthreads();
        #pragma unroll
        for (int i = 0; i < 16; ++i) {
            int idx = t + i*512; int k = idx >> 7, r = idx & 127;
            Af[U32_OFF + k*132 + r] = tmpf[i];
        }
        __syncthreads();
        #pragma unroll
        for (int i = 0; i < 16; ++i) {
            int idx = t + i*512; int k = idx >> 7, r = idx & 127;
            tmpf[i] = (float)Ad[(64+k)*NSTR + r];
        }
        __syncthreads();
        #pragma unroll
        for (int i = 0; i < 16; ++i) {
            int idx = t + i*512; int k = idx >> 7, r = idx & 127;
            Af[V32_OFF + k*132 + r] = tmpf[i];
        }
    }
    __syncthreads();

    // ---- MLP chain (fp32): relu chains; layer 3 also scales by sigma ----
    int SRCO = U32_OFF, DSTO = RA_OFF;
    const int n = t & 63, ib = (t >> 6)*16;
    for (int layer = 0; layer < 7; ++layer) {
        const float* wptr = (layer < 4) ? (w1g + layer*4096) : (w2g + (layer-3)*4096);
        for (int idx = t; idx < 4096; idx += 512) Af[WF_OFF + idx] = wptr[idx];
        __syncthreads();
        float acc[16];
        #pragma unroll
        for (int m = 0; m < 16; ++m) acc[m] = 0.f;
        for (int kk = 0; kk < 64; ++kk) {
            float wv = Af[WF_OFF + kk*64 + n];
            const float4* s4 = (const float4*)&Af[SRCO + kk*132 + ib];
            #pragma unroll
            for (int q4 = 0; q4 < 4; ++q4) {
                float4 v4 = s4[q4];
                acc[q4*4+0] = fmaf(v4.x, wv, acc[q4*4+0]);
                acc[q4*4+1] = fmaf(v4.y, wv, acc[q4*4+1]);
                acc[q4*4+2] = fmaf(v4.z, wv, acc[q4*4+2]);
                acc[q4*4+3] = fmaf(v4.w, wv, acc[q4*4+3]);
            }
        }
        float sc = (layer == 3) ? sigf[n] : 1.f;
        #pragma unroll
        for (int q4 = 0; q4 < 4; ++q4) {
            float4 o;
            o.x = fmaxf(acc[q4*4+0], 0.f)*sc;
            o.y = fmaxf(acc[q4*4+1], 0.f)*sc;
            o.z = fmaxf(acc[q4*4+2], 0.f)*sc;
            o.w = fmaxf(acc[q4*4+3], 0.f)*sc;
            ((float4*)&Af[DSTO + n*132 + ib])[q4] = o;
        }
        __syncthreads();
        SRCO = DSTO; DSTO = (DSTO == RA_OFF) ? RB_OFF : RA_OFF;
    }

    // ---- T = r @ Vh_st, write fp32 into this block's own M slot ----
    {
        float* Tb = (float*)((char*)wsM + (size_t)b*131072);
        const int j2 = t & 127, ih = (t >> 7)*32;
        float acc2[32];
        #pragma unroll
        for (int m = 0; m < 32; ++m) acc2[m] = 0.f;
        for (int kk = 0; kk < 64; ++kk) {
            float vv = Af[V32_OFF + kk*132 + j2];
            const float4* r4 = (const float4*)&Af[RA_OFF + kk*132 + ih];
            #pragma unroll
            for (int q4 = 0; q4 < 8; ++q4) {
                float4 v4 = r4[q4];
                acc2[q4*4+0] = fmaf(v4.x, vv, acc2[q4*4+0]);
                acc2[q4*4+1] = fmaf(v4.y, vv, acc2[q4*4+1]);
                acc2[q4*4+2] = fmaf(v4.z, vv, acc2[q4*4+2]);
                acc2[q4*4+3] = fmaf(v4.w, vv, acc2[q4*4+3]);
            }
        }
        #pragma unroll
        for (int m = 0; m < 32; ++m) Tb[(size_t)(ih+m)*128 + j2] = acc2[m];
    }
}

// ---------------- Stage 3: out = weightsO @ vec(T) per batch (K-split) ----------------
__global__ __launch_bounds__(256) void k_out(const char* __restrict__ wsbase,
        const float* __restrict__ wO, float* __restrict__ part)
{
    __shared__ float Wt[128*65];
    __shared__ float Tt[8*64];
    const int t = threadIdx.x;
    const int bt = blockIdx.x & 31, ks = blockIdx.x >> 5;
    const int a = t & 127, bh = (t >> 7)*4;
    float acc[4] = {0.f, 0.f, 0.f, 0.f};
    for (int cc = 0; cc < 32; ++cc) {
        const int kbase = ks*2048 + cc*64;
        __syncthreads();
        for (int idx = t; idx < 8192; idx += 256) {
            int aa = idx >> 6, nn = idx & 63;
            Wt[aa*65 + nn] = wO[aa*16384 + kbase + nn];
        }
        for (int idx = t; idx < 512; idx += 256) {
            int bl = idx >> 6, nn = idx & 63;
            const float* Tb = (const float*)(wsbase + (size_t)(bt*8 + bl)*131072);
            Tt[bl*64 + nn] = Tb[kbase + nn];
        }
        __syncthreads();
        for (int nn = 0; nn < 64; ++nn) {
            float wv = Wt[a*65 + nn];
            #pragma unroll
            for (int m = 0; m < 4; ++m) acc[m] = fmaf(Tt[(bh+m)*64 + nn], wv, acc[m]);
        }
    }
    #pragma unroll
    for (int m = 0; m < 4; ++m)
        part[ks*32768 + (bt*8 + bh + m)*128 + a] = acc[m];
}

__global__ __launch_bounds__(256) void k_red(const float* __restrict__ part,
                                             float* __restrict__ out)
{
    int i = blockIdx.x*256 + threadIdx.x;
    float s = 0.f;
    #pragma unroll
    for (int ks = 0; ks < 8; ++ks) s += part[ks*32768 + i];
    out[i] = s;
}

extern "C" void kernel_launch(void* const* d_in, const int* in_sizes, int n_in,
                              void* d_out, int out_size, void* d_ws, size_t ws_size,
                              hipStream_t stream)
{
    (void)in_sizes; (void)n_in; (void)out_size; (void)ws_size;
    const float* obs = (const float*)d_in[0];
    const float* w1  = (const float*)d_in[1];
    const float* w2  = (const float*)d_in[2];
    const float* wO  = (const float*)d_in[3];
    const float* c1w = (const float*)d_in[4];
    const float* c1b = (const float*)d_in[5];
    const float* c2w = (const float*)d_in[6];
    const float* c2b = (const float*)d_in[7];
    double* M = (double*)d_ws;
    float* part = (float*)((char*)d_ws + 33554432);

    k_feat<<<dim3(16384), dim3(256), 0, stream>>>(obs, c1w, c1b, c2w, c2b, M);
    k_svd <<<dim3(256),   dim3(512), 0, stream>>>(w1, w2, M);
    k_out <<<dim3(256),   dim3(256), 0, stream>>>((const char*)d_ws, wO, part);
    k_red <<<dim3(128),   dim3(256), 0, stream>>>(part, (float*)d_out);
}

// Round 3
// 2785.224 us; speedup vs baseline: 3.8881x; 1.3660x over previous
//
#include <hip/hip_runtime.h>

// ws layout (bytes):
//   [0, 33554432)            M as double, 256 blocks x 16384 (131072 B each).
//                            After k_svd, first 65536 B of each block's slot is
//                            overwritten with T as float (16384 floats).
//   [33554432, 34603008)     GEMM partials: 8 * 256 * 128 floats

#define NSTR 132               // double stride for 128-row columns in LDS (EVEN: 16B-aligned double2)
// float-phase offsets (in floats) inside the shared pool
#define U32_OFF 0
#define V32_OFF 8448
#define RA_OFF  16896
#define RB_OFF  25344
#define WF_OFF  33792
#define POOL_BYTES 151552      // 37888 floats; double phase needs 128*132*8 = 135168 B

// zero-cost fence: orders DS ops across sub-rounds within a wave (cross-lane
// same-wave RAW through LDS is NOT modeled by the compiler's per-lane alias
// analysis; the HW DS pipe is in-order per wave, so a compile-time fence is
// sufficient and free).
#define WAVE_FENCE() do { __asm__ __volatile__("" ::: "memory"); \
                          __builtin_amdgcn_wave_barrier();        \
                          __asm__ __volatile__("" ::: "memory"); } while (0)

// ---------------- Stage 1: features + conv chain -> M (fp64) ----------------
__global__ __launch_bounds__(256) void k_feat(const float* __restrict__ obs,
        const float* __restrict__ c1w, const float* __restrict__ c1b,
        const float* __restrict__ c2w, const float* __restrict__ c2b,
        double* __restrict__ M)
{
    __shared__ __align__(16) float lds[256*29];
    const int t = threadIdx.x;
    const float4* obs4 = (const float4*)obs;
    float4* lds4 = (float4*)lds;
    const size_t base4 = (size_t)blockIdx.x * 1856;
    for (int idx = t; idx < 1856; idx += 256) lds4[idx] = obs4[base4 + idx];
    __syncthreads();
    const float* o = &lds[t*29];
    double f0=0,f1=0,f2=0,f3=0,f4=0,f5=0;
    #pragma unroll
    for (int d=1; d<5; ++d) f0 += (double)o[d]*d;
    #pragma unroll
    for (int d=1; d<5; ++d) f1 += (double)o[5+d]*d;
    f2 = (double)o[11] + 2.0*(double)o[12];
    #pragma unroll
    for (int d=1; d<8; ++d) f3 += (double)o[13+d]*d;
    #pragma unroll
    for (int d=1; d<6; ++d) f4 += (double)o[21+d]*d;
    f5 = (double)o[28];
    const double w0=c1w[0], w1=c1w[1], w2=c1w[2], w3=c1w[3], b1=c1b[0];
    const double cw0=c2w[0], cw1=c2w[1], b2=c2b[0];
    // conv1 stride2 pad2 k4: 6 -> 4 -> 3 -> 2 ; conv2 k2: -> 1
    double y0 = b1 + f0*w2 + f1*w3;
    double y1 = b1 + f0*w0 + f1*w1 + f2*w2 + f3*w3;
    double y2 = b1 + f2*w0 + f3*w1 + f4*w2 + f5*w3;
    double y3 = b1 + f4*w0 + f5*w1;
    double z0 = b1 + y0*w2 + y1*w3;
    double z1 = b1 + y0*w0 + y1*w1 + y2*w2 + y3*w3;
    double z2 = b1 + y2*w0 + y3*w1;
    double u0 = b1 + z0*w2 + z1*w3;
    double u1 = b1 + z0*w0 + z1*w1 + z2*w2;
    double m  = b2 + u0*cw0 + u1*cw1;
    M[(size_t)blockIdx.x*256 + t] = m;
}

// ---------------- Stage 2: per-batch SVD + QR signs + MLP + T ----------------
__global__ __launch_bounds__(512, 2) void k_svd(
        const float* __restrict__ w1g, const float* __restrict__ w2g,
        double* __restrict__ wsM)
{
    __shared__ __align__(16) char smem[POOL_BYTES];
    double* Ad = (double*)smem;
    float*  Af = (float*)smem;
    __shared__ double sig_d[128];
    __shared__ double sigs_d[64];
    __shared__ float  sigf[64];
    __shared__ double tau[64];
    __shared__ double vjs[64];
    __shared__ int    perm[128];
    __shared__ int    redflag[8];
    __shared__ int    convflag;

    const int t = threadIdx.x;
    const int b = blockIdx.x;
    double* Mg = wsM + (size_t)b*16384;

    const int wv   = t >> 6;       // wave 0..7
    const int lk   = t & 63;       // lane in wave
    const int slot = lk >> 3;      // pair slot 0..7
    const int sub  = lk & 7;       // lane in slot

    // load M column-major into LDS (fp64)
    for (int idx = t; idx < 16384; idx += 512) {
        int r = idx >> 7, c = idx & 127;
        Ad[c*NSTR + r] = Mg[idx];
    }
    __syncthreads();

    // ---- hierarchical block-tournament one-sided Jacobi, fp64 ----
    // 16 groups of 8 columns. Per sweep: internal phase (each wave does the
    // 2*C(8,2)=56 internal pairs of its 2 groups, 7 sub-rounds) + 15 cross
    // rounds (tournament over 16 groups; each wave does its pair's 8x8 cross
    // pairs as 8 sub-rounds, own column held in registers). Barriers only at
    // round boundaries (16/sweep vs 127/sweep for the flat tournament).
    // Lane `sub` owns rows {16m+2sub, 16m+2sub+1}, m=0..7, as double2
    // (ds_read_b128): a slot's 8 lanes cover 32 consecutive dwords -> all 32
    // banks -> bank-minimal.
    for (int sweep = 0; sweep < 16; ++sweep) {
        int big = 0;

        // ---- internal phase: wave wv owns groups 2wv, 2wv+1 ----
        for (int r = 0; r < 7; ++r) {
            const int half = slot >> 2, i = slot & 3;
            int aa, bb;
            if (i == 0) { aa = 7; bb = r; }
            else { aa = (r + i) % 7; bb = (r - i + 7) % 7; }
            const int base = 16*wv + half*8;
            const int p = base + aa, q = base + bb;
            double2* Pp = (double2*)&Ad[p*NSTR + 2*sub];
            double2* Pq = (double2*)&Ad[q*NSTR + 2*sub];
            double2 xs[8], ys[8];
            double al = 0.0, be = 0.0, ga = 0.0;
            #pragma unroll
            for (int m = 0; m < 8; ++m) {
                double2 x = Pp[m*8], y = Pq[m*8];
                xs[m] = x; ys[m] = y;
                al = fma(x.x, x.x, al); al = fma(x.y, x.y, al);
                be = fma(y.x, y.x, be); be = fma(y.y, y.y, be);
                ga = fma(x.x, y.x, ga); ga = fma(x.y, y.y, ga);
            }
            al += __shfl_xor(al,1); be += __shfl_xor(be,1); ga += __shfl_xor(ga,1);
            al += __shfl_xor(al,2); be += __shfl_xor(be,2); ga += __shfl_xor(ga,2);
            al += __shfl_xor(al,4); be += __shfl_xor(be,4); ga += __shfl_xor(ga,4);
            double ab = al*be, g2 = ga*ga;
            big |= (g2 > ab*1e-20);
            if (g2 > ab*1e-28) {
                double zeta = (be - al) / (2.0*ga);
                double tt = ((zeta >= 0.0) ? 1.0 : -1.0) / (fabs(zeta) + sqrt(fma(zeta,zeta,1.0)));
                double cc = 1.0 / sqrt(fma(tt,tt,1.0));
                double ss = tt*cc;
                #pragma unroll
                for (int m = 0; m < 8; ++m) {
                    double2 np, nq;
                    np.x = fma(-ss, ys[m].x, cc*xs[m].x);
                    np.y = fma(-ss, ys[m].y, cc*xs[m].y);
                    nq.x = fma( ss, xs[m].x, cc*ys[m].x);
                    nq.y = fma( ss, xs[m].y, cc*ys[m].y);
                    Pp[m*8] = np;
                    Pq[m*8] = nq;
                }
            }
            WAVE_FENCE();
        }
        __syncthreads();

        // ---- cross phase: 15 tournament rounds over 16 groups ----
        for (int r = 0; r < 15; ++r) {
            int GI, GJ;
            if (wv == 0) { GI = 15; GJ = r; }
            else { GI = (r + wv) % 15; GJ = (r - wv + 15) % 15; }
            const int pcol = GI*8 + slot;
            double2* Pp = (double2*)&Ad[pcol*NSTR + 2*sub];
            double2 xr[8];
            #pragma unroll
            for (int m = 0; m < 8; ++m) xr[m] = Pp[m*8];
            for (int s = 0; s < 8; ++s) {
                const int qcol = GJ*8 + ((slot + s) & 7);
                double2* Pq = (double2*)&Ad[qcol*NSTR + 2*sub];
                double2 ys[8];
                double al = 0.0, be = 0.0, ga = 0.0;
                #pragma unroll
                for (int m = 0; m < 8; ++m) {
                    double2 x = xr[m], y = Pq[m*8];
                    ys[m] = y;
                    al = fma(x.x, x.x, al); al = fma(x.y, x.y, al);
                    be = fma(y.x, y.x, be); be = fma(y.y, y.y, be);
                    ga = fma(x.x, y.x, ga); ga = fma(x.y, y.y, ga);
                }
                al += __shfl_xor(al,1); be += __shfl_xor(be,1); ga += __shfl_xor(ga,1);
                al += __shfl_xor(al,2); be += __shfl_xor(be,2); ga += __shfl_xor(ga,2);
                al += __shfl_xor(al,4); be += __shfl_xor(be,4); ga += __shfl_xor(ga,4);
                double ab = al*be, g2 = ga*ga;
                big |= (g2 > ab*1e-20);
                if (g2 > ab*1e-28) {
                    double zeta = (be - al) / (2.0*ga);
                    double tt = ((zeta >= 0.0) ? 1.0 : -1.0) / (fabs(zeta) + sqrt(fma(zeta,zeta,1.0)));
                    double cc = 1.0 / sqrt(fma(tt,tt,1.0));
                    double ss = tt*cc;
                    #pragma unroll
                    for (int m = 0; m < 8; ++m) {
                        double2 x = xr[m], y = ys[m];
                        double2 np, nq;
                        np.x = fma(-ss, y.x, cc*x.x);
                        np.y = fma(-ss, y.y, cc*x.y);
                        nq.x = fma( ss, x.x, cc*y.x);
                        nq.y = fma( ss, x.y, cc*y.y);
                        xr[m] = np;
                        Pq[m*8] = nq;
                    }
                }
                WAVE_FENCE();
            }
            #pragma unroll
            for (int m = 0; m < 8; ++m) Pp[m*8] = xr[m];
            __syncthreads();
        }

        // ---- convergence check ----
        unsigned long long bb = __ballot(big);
        if (lk == 0) redflag[wv] = (bb != 0ULL) ? 1 : 0;
        __syncthreads();
        if (t == 0) {
            int any = 0;
            for (int i = 0; i < 8; ++i) any |= redflag[i];
            convflag = !any;
        }
        __syncthreads();
        if (convflag) break;
    }
    __syncthreads();

    // ---- column norms, sort descending ----
    if (t < 128) {
        double s = 0.0;
        for (int r = 0; r < 128; ++r) { double v = Ad[t*NSTR + r]; s = fma(v, v, s); }
        sig_d[t] = sqrt(s);
    }
    __syncthreads();
    if (t < 128) {
        double my = sig_d[t]; int rk = 0;
        for (int c = 0; c < 128; ++c) {
            double v = sig_d[c];
            rk += (v > my) || (v == my && c < t);
        }
        perm[rk] = t;
    }
    __syncthreads();
    if (t < 64) { sigs_d[t] = sig_d[perm[t]]; sigf[t] = (float)sig_d[perm[t]]; }
    __syncthreads();

    // ---- compact U64 = A[:,perm[k]]/sigma into cols 0..63 (register-staged) ----
    {
        double tmp[16];
        #pragma unroll
        for (int i = 0; i < 16; ++i) {
            int idx = t + i*512; int k = idx >> 7, r = idx & 127;
            tmp[i] = Ad[perm[k]*NSTR + r] / sigs_d[k];
        }
        __syncthreads();
        #pragma unroll
        for (int i = 0; i < 16; ++i) {
            int idx = t + i*512; int k = idx >> 7, r = idx & 127;
            Ad[k*NSTR + r] = tmp[i];
        }
    }
    __syncthreads();

    // ---- V64 = M^T * U64 * Sigma^{-1} into cols 64..127 ----
    {
        const int j = t & 127, kh = (t >> 7)*16;
        double acc[16];
        #pragma unroll
        for (int m = 0; m < 16; ++m) acc[m] = 0.0;
        for (int r = 0; r < 128; ++r) {
            double mv = Mg[r*128 + j];
            #pragma unroll
            for (int m = 0; m < 16; ++m) acc[m] = fma(mv, Ad[(kh+m)*NSTR + r], acc[m]);
        }
        #pragma unroll
        for (int m = 0; m < 16; ++m) Ad[(64+kh+m)*NSTR + j] = acc[m] / sigs_d[kh+m];
    }
    __syncthreads();

    // ---- Householder QR (LAPACK sign convention) + org2r rebuild, in place ----
    // After this, cols 0..63 = U_st (= Q of qr(U64)) and cols 64..127 = Vq.
    for (int which = 0; which < 2; ++which) {
        const int CB = which ? 64 : 0;
        // geqrf
        for (int j = 0; j < 64; ++j) {
            if (t < 64) {
                double ps = 0.0;
                for (int r = j + t; r < 128; r += 64) { double v = Ad[(CB+j)*NSTR + r]; ps = fma(v, v, ps); }
                #pragma unroll
                for (int off = 1; off < 64; off <<= 1) ps += __shfl_xor(ps, off);
                if (t == 0) {
                    double piv = Ad[(CB+j)*NSTR + j];
                    double nx = sqrt(ps);
                    double vj = piv + ((piv >= 0.0) ? nx : -nx);
                    double vn2 = ps - piv*piv + vj*vj;
                    tau[j] = 2.0 / vn2;
                    vjs[j] = vj;
                    Ad[(CB+j)*NSTR + j] = vj;
                }
            }
            __syncthreads();
            {
                int g = t >> 3, c = j + 1 + g;
                if (c < 64) {
                    double w = 0.0;
                    for (int r = j + sub; r < 128; r += 8)
                        w = fma(Ad[(CB+j)*NSTR + r], Ad[(CB+c)*NSTR + r], w);
                    w += __shfl_xor(w,1); w += __shfl_xor(w,2); w += __shfl_xor(w,4);
                    w *= tau[j];
                    for (int r = j + sub; r < 128; r += 8)
                        Ad[(CB+c)*NSTR + r] -= w * Ad[(CB+j)*NSTR + r];
                }
            }
            __syncthreads();
        }
        // org2r (backward accumulation): Q = H_0 ... H_63 * E
        for (int j = 63; j >= 0; --j) {
            {
                int g = t >> 3, c = j + 1 + g;
                if (c < 64) {
                    double w = 0.0;
                    for (int r = j + sub; r < 128; r += 8)
                        w = fma(Ad[(CB+j)*NSTR + r], Ad[(CB+c)*NSTR + r], w);
                    w += __shfl_xor(w,1); w += __shfl_xor(w,2); w += __shfl_xor(w,4);
                    w *= tau[j];
                    for (int r = j + sub; r < 128; r += 8)
                        Ad[(CB+c)*NSTR + r] -= w * Ad[(CB+j)*NSTR + r];
                }
            }
            __syncthreads();
            if (t < 128) {
                double qv;
                if (t < j) qv = 0.0;
                else {
                    double vt = Ad[(CB+j)*NSTR + t];
                    qv = ((t == j) ? 1.0 : 0.0) - tau[j]*vjs[j]*vt;
                }
                Ad[(CB+j)*NSTR + t] = qv;
            }
            __syncthreads();
        }
    }

    // ---- downcast U_st, Vq to fp32 (register-staged, regions overlap) ----
    {
        float tmpf[16];
        #pragma unroll
        for (int i = 0; i < 16; ++i) {
            int idx = t + i*512; int k = idx >> 7, r = idx & 127;
            tmpf[i] = (float)Ad[k*NSTR + r];
        }
        __syncthreads();
        #pragma unroll
        for (int i = 0; i < 16; ++i) {
            int idx = t + i*512; int k = idx >> 7, r = idx & 127;
            Af[U32_OFF + k*132 + r] = tmpf[i];
        }
        __syncthreads();
        #pragma unroll
        for (int i = 0; i < 16; ++i) {
            int idx = t + i*512; int k = idx >> 7, r = idx & 127;
            tmpf[i] = (float)Ad[(64+k)*NSTR + r];
        }
        __syncthreads();
        #pragma unroll
        for (int i = 0; i < 16; ++i) {
            int idx = t + i*512; int k = idx >> 7, r = idx & 127;
            Af[V32_OFF + k*132 + r] = tmpf[i];
        }
    }
    __syncthreads();

    // ---- MLP chain (fp32): relu chains; layer 3 also scales by sigma ----
    int SRCO = U32_OFF, DSTO = RA_OFF;
    const int n = t & 63, ib = (t >> 6)*16;
    for (int layer = 0; layer < 7; ++layer) {
        const float* wptr = (layer < 4) ? (w1g + layer*4096) : (w2g + (layer-3)*4096);
        for (int idx = t; idx < 4096; idx += 512) Af[WF_OFF + idx] = wptr[idx];
        __syncthreads();
        float acc[16];
        #pragma unroll
        for (int m = 0; m < 16; ++m) acc[m] = 0.f;
        for (int kk = 0; kk < 64; ++kk) {
            float wv2 = Af[WF_OFF + kk*64 + n];
            const float4* s4 = (const float4*)&Af[SRCO + kk*132 + ib];
            #pragma unroll
            for (int q4 = 0; q4 < 4; ++q4) {
                float4 v4 = s4[q4];
                acc[q4*4+0] = fmaf(v4.x, wv2, acc[q4*4+0]);
                acc[q4*4+1] = fmaf(v4.y, wv2, acc[q4*4+1]);
                acc[q4*4+2] = fmaf(v4.z, wv2, acc[q4*4+2]);
                acc[q4*4+3] = fmaf(v4.w, wv2, acc[q4*4+3]);
            }
        }
        float sc = (layer == 3) ? sigf[n] : 1.f;
        #pragma unroll
        for (int q4 = 0; q4 < 4; ++q4) {
            float4 o;
            o.x = fmaxf(acc[q4*4+0], 0.f)*sc;
            o.y = fmaxf(acc[q4*4+1], 0.f)*sc;
            o.z = fmaxf(acc[q4*4+2], 0.f)*sc;
            o.w = fmaxf(acc[q4*4+3], 0.f)*sc;
            ((float4*)&Af[DSTO + n*132 + ib])[q4] = o;
        }
        __syncthreads();
        SRCO = DSTO; DSTO = (DSTO == RA_OFF) ? RB_OFF : RA_OFF;
    }

    // ---- T = r @ Vh_st, write fp32 into this block's own M slot ----
    {
        float* Tb = (float*)((char*)wsM + (size_t)b*131072);
        const int j2 = t & 127, ih = (t >> 7)*32;
        float acc2[32];
        #pragma unroll
        for (int m = 0; m < 32; ++m) acc2[m] = 0.f;
        for (int kk = 0; kk < 64; ++kk) {
            float vv = Af[V32_OFF + kk*132 + j2];
            const float4* r4 = (const float4*)&Af[RA_OFF + kk*132 + ih];
            #pragma unroll
            for (int q4 = 0; q4 < 8; ++q4) {
                float4 v4 = r4[q4];
                acc2[q4*4+0] = fmaf(v4.x, vv, acc2[q4*4+0]);
                acc2[q4*4+1] = fmaf(v4.y, vv, acc2[q4*4+1]);
                acc2[q4*4+2] = fmaf(v4.z, vv, acc2[q4*4+2]);
                acc2[q4*4+3] = fmaf(v4.w, vv, acc2[q4*4+3]);
            }
        }
        #pragma unroll
        for (int m = 0; m < 32; ++m) Tb[(size_t)(ih+m)*128 + j2] = acc2[m];
    }
}

// ---------------- Stage 3: out = weightsO @ vec(T) per batch (K-split) ----------------
__global__ __launch_bounds__(256) void k_out(const char* __restrict__ wsbase,
        const float* __restrict__ wO, float* __restrict__ part)
{
    __shared__ float Wt[128*65];
    __shared__ float Tt[8*64];
    const int t = threadIdx.x;
    const int bt = blockIdx.x & 31, ks = blockIdx.x >> 5;
    const int a = t & 127, bh = (t >> 7)*4;
    float acc[4] = {0.f, 0.f, 0.f, 0.f};
    for (int cc = 0; cc < 32; ++cc) {
        const int kbase = ks*2048 + cc*64;
        __syncthreads();
        for (int idx = t; idx < 8192; idx += 256) {
            int aa = idx >> 6, nn = idx & 63;
            Wt[aa*65 + nn] = wO[aa*16384 + kbase + nn];
        }
        for (int idx = t; idx < 512; idx += 256) {
            int bl = idx >> 6, nn = idx & 63;
            const float* Tb = (const float*)(wsbase + (size_t)(bt*8 + bl)*131072);
            Tt[bl*64 + nn] = Tb[kbase + nn];
        }
        __syncthreads();
        for (int nn = 0; nn < 64; ++nn) {
            float wv = Wt[a*65 + nn];
            #pragma unroll
            for (int m = 0; m < 4; ++m) acc[m] = fmaf(Tt[(bh+m)*64 + nn], wv, acc[m]);
        }
    }
    #pragma unroll
    for (int m = 0; m < 4; ++m)
        part[ks*32768 + (bt*8 + bh + m)*128 + a] = acc[m];
}

__global__ __launch_bounds__(256) void k_red(const float* __restrict__ part,
                                             float* __restrict__ out)
{
    int i = blockIdx.x*256 + threadIdx.x;
    float s = 0.f;
    #pragma unroll
    for (int ks = 0; ks < 8; ++ks) s += part[ks*32768 + i];
    out[i] = s;
}

extern "C" void kernel_launch(void* const* d_in, const int* in_sizes, int n_in,
                              void* d_out, int out_size, void* d_ws, size_t ws_size,
                              hipStream_t stream)
{
    (void)in_sizes; (void)n_in; (void)out_size; (void)ws_size;
    const float* obs = (const float*)d_in[0];
    const float* w1  = (const float*)d_in[1];
    const float* w2  = (const float*)d_in[2];
    const float* wO  = (const float*)d_in[3];
    const float* c1w = (const float*)d_in[4];
    const float* c1b = (const float*)d_in[5];
    const float* c2w = (const float*)d_in[6];
    const float* c2b = (const float*)d_in[7];
    double* M = (double*)d_ws;
    float* part = (float*)((char*)d_ws + 33554432);

    k_feat<<<dim3(16384), dim3(256), 0, stream>>>(obs, c1w, c1b, c2w, c2b, M);
    k_svd <<<dim3(256),   dim3(512), 0, stream>>>(w1, w2, M);
    k_out <<<dim3(256),   dim3(256), 0, stream>>>((const char*)d_ws, wO, part);
    k_red <<<dim3(128),   dim3(256), 0, stream>>>(part, (float*)d_out);
}